// Round 1
// baseline (556.903 us; speedup 1.0000x reference)
//
#include <hip/hip_runtime.h>

// SpectralConv2d: DHT-based spectral conv, B=16, Cin=Cout=64, H=W=128, modes 20x20.
// Pipeline (all linear, blurs folded):
//  K0: Wp/Wm = 0.5*(w1 +/- w1(-k)) / 16384, pre-blurred over Cout axis
//  K1: per-row forward transform  Pw[b,c,n1,k2] = sum_n2 x * e^{+2pi i k2 n2/128}
//  K2: Zf over n1, combine -> X1[m][b][c] (dht modes, 20x20)
//  K2b: blur X1 over batch axis
//  K3: per-mode channel mix: O[b,o,m] = sum_c X1b*Wp + X1b(-m)*Wm
//  K4: G[b,o,k1,v] = sum_k2 O * e^{+2pi i v k2/128}
//  K5: per (b,o,v-strip): Z over k1 -> y_pre, blur-u (H), blur-v (W) w/ halo, mask, write

#define TWO_PI 6.283185307179586f

__device__ __forceinline__ void gauss9(float* g) {
  float s = 0.f;
#pragma unroll
  for (int t = 0; t < 9; ++t) { float d = (float)(t - 4); g[t] = expf(-0.5f * d * d); s += g[t]; }
  float inv = 1.f / s;
#pragma unroll
  for (int t = 0; t < 9; ++t) g[t] *= inv;
}

// ---- K0: weight prep: Wp/Wm[(m*64+c)*64+o], blurred over o, scaled 0.5/16384
__global__ void k0_weights(const float* __restrict__ w1, float* __restrict__ Wp,
                           float* __restrict__ Wm) {
  int idx = blockIdx.x * 256 + threadIdx.x;
  if (idx >= 400 * 64 * 64) return;
  int o = idx & 63, c = (idx >> 6) & 63, m = idx >> 12;
  int i = m / 20, j = m - i * 20;
  int ni = (20 - i) % 20, nj = (20 - j) % 20;
  float g[9]; gauss9(g);
  float s = 0.f, d = 0.f;
#pragma unroll
  for (int t = 0; t < 9; ++t) {
    int oc = o - 4 + t; oc = oc < 0 ? 0 : (oc > 63 ? 63 : oc);
    float a = w1[((c * 64 + oc) * 20 + i) * 20 + j];
    float b = w1[((c * 64 + oc) * 20 + ni) * 20 + nj];
    s += g[t] * (a + b);
    d += g[t] * (a - b);
  }
  const float sc = 0.5f / 16384.0f;
  Wp[(m * 64 + c) * 64 + o] = s * sc;
  Wm[(m * 64 + c) * 64 + o] = d * sc;
}

// ---- K1: one block (128 thr) per row r=(b*64+c)*128+n1; Pw[(r*20+k2)*2+{re,im}]
__global__ void k1_rows(const float* __restrict__ x, float* __restrict__ Pw) {
  __shared__ float row[128];
  __shared__ float ct[128];
  int r = blockIdx.x;
  int tid = threadIdx.x;
  ct[tid] = cosf(TWO_PI * (float)tid * (1.0f / 128.0f));
  row[tid] = x[r * 128 + tid];
  __syncthreads();
  if (tid < 40) {
    int k2 = tid >> 1, part = tid & 1;  // 0: cos, 1: sin
    int ph = part ? 96 : 0;             // sin(2pi j/128) = cos(2pi (j+96)/128)
    float acc = 0.f;
#pragma unroll 8
    for (int n2 = 0; n2 < 128; ++n2) {
      acc += row[n2] * ct[ph];
      ph = (ph + k2) & 127;
    }
    Pw[(r * 20 + k2) * 2 + part] = acc;
  }
}

// ---- K2: one block (256 thr) per (b,c); X1[m*1024 + b*64 + c]
__global__ void k2_modes(const float* __restrict__ Pw, float* __restrict__ X1) {
  __shared__ float2 P[128 * 20];
  __shared__ float ct[128];
  int bc = blockIdx.x, tid = threadIdx.x;
  if (tid < 128) ct[tid] = cosf(TWO_PI * (float)tid * (1.0f / 128.0f));
  const float2* Pin = (const float2*)Pw;
  for (int t = tid; t < 2560; t += 256) P[t] = Pin[bc * 2560 + t];
  __syncthreads();
  for (int m = tid; m < 400; m += 256) {
    int k1 = m / 20, k2 = m - k1 * 20;
    float zr = 0.f, zi = 0.f;
    int ph = 0;
#pragma unroll 8
    for (int n1 = 0; n1 < 128; ++n1) {
      float c = ct[ph], sn = ct[(ph + 96) & 127];
      float2 p = P[n1 * 20 + k2];
      zr += c * p.x - sn * p.y;
      zi += c * p.y + sn * p.x;
      ph = (ph + k1) & 127;
    }
    int pm = (k1 + k2) & 127;
    float v = zr - ct[(pm + 96) & 127] * zr - ct[pm] * zi;
    X1[m * 1024 + bc] = v;
  }
}

// ---- K2b: blur over batch axis (16, clamp), same layout
__global__ void k2b_blurB(const float* __restrict__ X1, float* __restrict__ X1b) {
  int idx = blockIdx.x * 256 + threadIdx.x;
  if (idx >= 400 * 16 * 64) return;
  int c = idx & 63, b = (idx >> 6) & 15, m = idx >> 10;
  float g[9]; gauss9(g);
  float acc = 0.f;
#pragma unroll
  for (int t = 0; t < 9; ++t) {
    int bb = b - 4 + t; bb = bb < 0 ? 0 : (bb > 15 ? 15 : bb);
    acc += g[t] * X1[m * 1024 + bb * 64 + c];
  }
  X1b[idx] = acc;
}

// ---- K3: one block (256 thr) per mode m; O[(b*64+o)*400 + m]
__global__ void k3_mix(const float* __restrict__ X1b, const float* __restrict__ Wp,
                       const float* __restrict__ Wm, float* __restrict__ O) {
  __shared__ float Xa[1024], Xn[1024];
  int m = blockIdx.x, tid = threadIdx.x;
  int i = m / 20, j = m - i * 20;
  int nm = ((20 - i) % 20) * 20 + ((20 - j) % 20);
  for (int t = tid; t < 1024; t += 256) {
    Xa[t] = X1b[m * 1024 + t];
    Xn[t] = X1b[nm * 1024 + t];
  }
  __syncthreads();
  int o = tid & 63, b0 = tid >> 6;  // b = b0, b0+4, b0+8, b0+12
  float acc[4] = {0.f, 0.f, 0.f, 0.f};
  for (int c = 0; c < 64; ++c) {
    float wp = Wp[(m * 64 + c) * 64 + o];
    float wm = Wm[(m * 64 + c) * 64 + o];
#pragma unroll
    for (int q = 0; q < 4; ++q) {
      int b = b0 + q * 4;
      acc[q] += Xa[b * 64 + c] * wp + Xn[b * 64 + c] * wm;
    }
  }
#pragma unroll
  for (int q = 0; q < 4; ++q) {
    int b = b0 + q * 4;
    O[(b * 64 + o) * 400 + m] = acc[q];
  }
}

// ---- K4: one block (256 thr) per (b,o); G[(bo*20+k1)*128+v] complex
__global__ void k4_cols(const float* __restrict__ O, float* __restrict__ G) {
  __shared__ float Om[400];
  __shared__ float ct[128];
  int bo = blockIdx.x, tid = threadIdx.x;
  if (tid < 128) ct[tid] = cosf(TWO_PI * (float)tid * (1.0f / 128.0f));
  for (int t = tid; t < 400; t += 256) Om[t] = O[bo * 400 + t];
  __syncthreads();
  float2* Gout = (float2*)G;
  for (int s = tid; s < 2560; s += 256) {
    int k1 = s >> 7, v = s & 127;
    float gr = 0.f, gi = 0.f;
    int ph = 0;
#pragma unroll
    for (int k2 = 0; k2 < 20; ++k2) {
      float val = Om[k1 * 20 + k2];
      gr += val * ct[ph];
      gi += val * ct[(ph + 96) & 127];
      ph = (ph + v) & 127;
    }
    Gout[bo * 2560 + s] = make_float2(gr, gi);
  }
}

// ---- K5: one block (256 thr) per (b,o) x 32-col strip; blur-u, blur-v (halo 4), mask
__global__ void k5_final(const float* __restrict__ G, float* __restrict__ out) {
  __shared__ float2 Gs[20][40];
  __shared__ float ct[128];
  __shared__ float R[40][128];   // y_pre, [slot][u]
  __shared__ float S[128][41];   // after blur-u, [u][slot] (+1 pad)
  int blk = blockIdx.x;
  int strip = blk & 3, bo = blk >> 2;
  int v0 = strip * 32;
  int tid = threadIdx.x;
  float g[9]; gauss9(g);
  if (tid < 128) ct[tid] = cosf(TWO_PI * (float)tid * (1.0f / 128.0f));
  const float2* Gin = (const float2*)G;
  for (int t = tid; t < 800; t += 256) {
    int k1 = t / 40, i = t - k1 * 40;
    int vc = v0 - 4 + i; vc = vc < 0 ? 0 : (vc > 127 ? 127 : vc);
    Gs[k1][i] = Gin[bo * 2560 + k1 * 128 + vc];
  }
  __syncthreads();
  // y_pre(u, vc(i)) = Zr - sin(phi)*Zr - cos(phi)*Zi, phi = 2pi(u+vc)/128
  for (int s = tid; s < 5120; s += 256) {
    int i = s >> 7, u = s & 127;
    int vc = v0 - 4 + i; vc = vc < 0 ? 0 : (vc > 127 ? 127 : vc);
    float zr = 0.f, zi = 0.f;
    int ph = 0;
#pragma unroll
    for (int k1 = 0; k1 < 20; ++k1) {
      float c = ct[ph], sn = ct[(ph + 96) & 127];
      float2 gv = Gs[k1][i];
      zr += c * gv.x - sn * gv.y;
      zi += c * gv.y + sn * gv.x;
      ph = (ph + u) & 127;
    }
    float cu = ct[u], su = ct[(u + 96) & 127];
    float cv = ct[vc], sv = ct[(vc + 96) & 127];
    float sphi = su * cv + cu * sv;
    float cphi = cu * cv - su * sv;
    R[i][u] = zr - sphi * zr - cphi * zi;
  }
  __syncthreads();
  // blur along u (H axis), edge clamp
  for (int s = tid; s < 5120; s += 256) {
    int i = s >> 7, u = s & 127;
    float acc = 0.f;
#pragma unroll
    for (int t = 0; t < 9; ++t) {
      int uc = u - 4 + t; uc = uc < 0 ? 0 : (uc > 127 ? 127 : uc);
      acc += g[t] * R[i][uc];
    }
    S[u][i] = acc;
  }
  __syncthreads();
  // blur along v (W axis) via halo slots + low-pass mask, write
  for (int s = tid; s < 4096; s += 256) {
    int jj = s & 31, u = s >> 5;
    int v = v0 + jj;
    float acc = 0.f;
#pragma unroll
    for (int t = 0; t < 9; ++t) acc += g[t] * S[u][jj + t];
    bool keep = (v <= 32) || (v >= 96);
    out[bo * 16384 + u * 128 + v] = keep ? acc : 0.f;
  }
}

extern "C" void kernel_launch(void* const* d_in, const int* in_sizes, int n_in,
                              void* d_out, int out_size, void* d_ws, size_t ws_size,
                              hipStream_t stream) {
  const float* x = (const float*)d_in[0];    // (16,64,128,128)
  const float* w1 = (const float*)d_in[1];   // (64,64,20,20)
  float* out = (float*)d_out;                // (16,64,128,128)
  float* ws = (float*)d_ws;

  float* Wp = ws;                 // 1,638,400
  float* Wm = Wp + 1638400;       // 1,638,400
  float* Pw = Wm + 1638400;       // 5,242,880 (float2 x 2,621,440)
  float* X1 = Pw + 5242880;       // 409,600
  float* X1b = X1 + 409600;       // 409,600
  float* O = X1b + 409600;        // 409,600
  float* G = O + 409600;          // 5,242,880
  // total ~60 MB

  hipLaunchKernelGGL(k0_weights, dim3(6400), dim3(256), 0, stream, w1, Wp, Wm);
  hipLaunchKernelGGL(k1_rows, dim3(16 * 64 * 128), dim3(128), 0, stream, x, Pw);
  hipLaunchKernelGGL(k2_modes, dim3(1024), dim3(256), 0, stream, Pw, X1);
  hipLaunchKernelGGL(k2b_blurB, dim3(1600), dim3(256), 0, stream, X1, X1b);
  hipLaunchKernelGGL(k3_mix, dim3(400), dim3(256), 0, stream, X1b, Wp, Wm, O);
  hipLaunchKernelGGL(k4_cols, dim3(1024), dim3(256), 0, stream, O, G);
  hipLaunchKernelGGL(k5_final, dim3(4096), dim3(256), 0, stream, G, out);
}

// Round 2
// 360.954 us; speedup vs baseline: 1.5429x; 1.5429x over previous
//
#include <hip/hip_runtime.h>

// SpectralConv2d DHT spectral conv, B=16, Cin=Cout=64, H=W=128, modes 20x20.
// Pipeline (all linear, all blurs folded into bases/weights):
//  k0:  Wp/Wm = 0.5*(w1 +/- w1(-k)) / 16384, pre-blurred over Cout
//  k1:  Pw[r][2k2+part] = sum_n2 x[r][n2] * {cos,sin}(theta k2 n2)   (GEMM 131072x40x128)
//  k2:  modes X1[m][b][c] from Pw (n1-contraction + DHT combine)
//  k2b: blur X1 over batch axis
//  k3:  channel mix O[b,o,m] = sum_c X1b*Wp + X1b(-m)*Wm
//  kinit: constant bases: Lg[80][128] (blur-u + signs), RBg[80][128] (blur-v + mask)
//  k5b: per (b,o): R = O*RB (in LDS), Y = L*R, store.
//  Identity: y(u,v) = sum O[k1,k2][cos(th(u k1+v k2)) - sin(th(u(k1+1)+v(k2+1)))]

#define TWO_PI 6.283185307179586f
#define THETA (TWO_PI / 128.0f)

__device__ __forceinline__ void gauss9(float* g) {
  float s = 0.f;
#pragma unroll
  for (int t = 0; t < 9; ++t) { float d = (float)(t - 4); g[t] = expf(-0.5f * d * d); s += g[t]; }
  float inv = 1.f / s;
#pragma unroll
  for (int t = 0; t < 9; ++t) g[t] *= inv;
}

// ---- k0: weight prep: Wp/Wm[(m*64+c)*64+o], blurred over o, scaled 0.5/16384
__global__ void k0_weights(const float* __restrict__ w1, float* __restrict__ Wp,
                           float* __restrict__ Wm) {
  int idx = blockIdx.x * 256 + threadIdx.x;
  if (idx >= 400 * 64 * 64) return;
  int o = idx & 63, c = (idx >> 6) & 63, m = idx >> 12;
  int i = m / 20, j = m - i * 20;
  int ni = (20 - i) % 20, nj = (20 - j) % 20;
  float g[9]; gauss9(g);
  float s = 0.f, d = 0.f;
#pragma unroll
  for (int t = 0; t < 9; ++t) {
    int oc = o - 4 + t; oc = oc < 0 ? 0 : (oc > 63 ? 63 : oc);
    float a = w1[((c * 64 + oc) * 20 + i) * 20 + j];
    float b = w1[((c * 64 + oc) * 20 + ni) * 20 + nj];
    s += g[t] * (a + b);
    d += g[t] * (a - b);
  }
  const float sc = 0.5f / 16384.0f;
  Wp[(m * 64 + c) * 64 + o] = s * sc;
  Wm[(m * 64 + c) * 64 + o] = d * sc;
}

// ---- k1 v2: GEMM Pw[131072 rows][40] = x[rows][128] * T[128][40]
// block: 192 threads, covers 64 rows x 40 cols; thread tile 4r x 4c (160 active)
__global__ void k1_rows(const float* __restrict__ x, float* __restrict__ Pw) {
  __shared__ float xs[128][68];   // col-major x tile: [n2][row], pad 68 for b128 align
  __shared__ float Ts[128][40];   // basis: [n2][2*k2+part]
  int tid = threadIdx.x;
  long row0 = (long)blockIdx.x * 64;
  // stage x (transpose to col-major)
  for (int t = tid; t < 8192; t += 192) {
    int r = t >> 7, n2 = t & 127;
    xs[n2][r] = x[(row0 + r) * 128 + n2];
  }
  // build T
  for (int t = tid; t < 5120; t += 192) {
    int n2 = t / 40, col = t - n2 * 40;
    int k2 = col >> 1;
    int p = (n2 * k2) & 127;
    float a = (float)p * THETA;
    Ts[n2][col] = (col & 1) ? sinf(a) : cosf(a);
  }
  __syncthreads();
  if (tid >= 160) return;
  int rg = tid / 10, cg = tid - rg * 10;
  int r0 = rg * 4, c0 = cg * 4;
  float acc[4][4];
#pragma unroll
  for (int i = 0; i < 4; ++i)
#pragma unroll
    for (int j = 0; j < 4; ++j) acc[i][j] = 0.f;
  for (int n2 = 0; n2 < 128; ++n2) {
    float4 xv = *(const float4*)&xs[n2][r0];
    float4 tv = *(const float4*)&Ts[n2][c0];
    float xr[4] = {xv.x, xv.y, xv.z, xv.w};
    float tr[4] = {tv.x, tv.y, tv.z, tv.w};
#pragma unroll
    for (int i = 0; i < 4; ++i)
#pragma unroll
      for (int j = 0; j < 4; ++j) acc[i][j] += xr[i] * tr[j];
  }
#pragma unroll
  for (int i = 0; i < 4; ++i) {
    float4 st = make_float4(acc[i][0], acc[i][1], acc[i][2], acc[i][3]);
    *(float4*)&Pw[(row0 + r0 + i) * 40 + c0] = st;
  }
}

// ---- k2: one block (256 thr) per (b,c); X1[m*1024 + b*64 + c]
__global__ void k2_modes(const float* __restrict__ Pw, float* __restrict__ X1) {
  __shared__ float2 P[128 * 20];
  __shared__ float ct[128];
  int bc = blockIdx.x, tid = threadIdx.x;
  if (tid < 128) ct[tid] = cosf(TWO_PI * (float)tid * (1.0f / 128.0f));
  const float2* Pin = (const float2*)Pw;
  for (int t = tid; t < 2560; t += 256) P[t] = Pin[bc * 2560 + t];
  __syncthreads();
  for (int m = tid; m < 400; m += 256) {
    int k1 = m / 20, k2 = m - k1 * 20;
    float zr = 0.f, zi = 0.f;
    int ph = 0;
#pragma unroll 8
    for (int n1 = 0; n1 < 128; ++n1) {
      float c = ct[ph], sn = ct[(ph + 96) & 127];
      float2 p = P[n1 * 20 + k2];
      zr += c * p.x - sn * p.y;
      zi += c * p.y + sn * p.x;
      ph = (ph + k1) & 127;
    }
    int pm = (k1 + k2) & 127;
    float v = zr - ct[(pm + 96) & 127] * zr - ct[pm] * zi;
    X1[m * 1024 + bc] = v;
  }
}

// ---- k2b: blur over batch axis (16, clamp)
__global__ void k2b_blurB(const float* __restrict__ X1, float* __restrict__ X1b) {
  int idx = blockIdx.x * 256 + threadIdx.x;
  if (idx >= 400 * 16 * 64) return;
  int c = idx & 63, b = (idx >> 6) & 15, m = idx >> 10;
  float g[9]; gauss9(g);
  float acc = 0.f;
#pragma unroll
  for (int t = 0; t < 9; ++t) {
    int bb = b - 4 + t; bb = bb < 0 ? 0 : (bb > 15 ? 15 : bb);
    acc += g[t] * X1[m * 1024 + bb * 64 + c];
  }
  X1b[idx] = acc;
}

// ---- k3: one block (256 thr) per mode m; O[(b*64+o)*400 + m]
__global__ void k3_mix(const float* __restrict__ X1b, const float* __restrict__ Wp,
                       const float* __restrict__ Wm, float* __restrict__ O) {
  __shared__ float Xa[1024], Xn[1024];
  int m = blockIdx.x, tid = threadIdx.x;
  int i = m / 20, j = m - i * 20;
  int nm = ((20 - i) % 20) * 20 + ((20 - j) % 20);
  for (int t = tid; t < 1024; t += 256) {
    Xa[t] = X1b[m * 1024 + t];
    Xn[t] = X1b[nm * 1024 + t];
  }
  __syncthreads();
  int o = tid & 63, b0 = tid >> 6;
  float acc[4] = {0.f, 0.f, 0.f, 0.f};
  for (int c = 0; c < 64; ++c) {
    float wp = Wp[(m * 64 + c) * 64 + o];
    float wm = Wm[(m * 64 + c) * 64 + o];
#pragma unroll
    for (int q = 0; q < 4; ++q) {
      int b = b0 + q * 4;
      acc[q] += Xa[b * 64 + c] * wp + Xn[b * 64 + c] * wm;
    }
  }
#pragma unroll
  for (int q = 0; q < 4; ++q) {
    int b = b0 + q * 4;
    O[(b * 64 + o) * 400 + m] = acc[q];
  }
}

// ---- kinit: constant bases. Lg[t=k+20q][u] (blur-u, signs folded, transposed),
//             RBg[t=k2+20q][v] (blur-v, mask folded).
// raw cols t: q0=cos(th*u*k), q1=sin(th*u*k), q2=sin(th*u*(k+1)), q3=cos(th*u*(k+1))
// L pairs:  +q0, -q1, -q2, -q3.  RB rows use swapped source: q0->raw0, q1->raw1,
// q2->raw3 (cos k+1), q3->raw2 (sin k+1).
__global__ void kinit(float* __restrict__ Lg, float* __restrict__ RBg) {
  __shared__ float raw[128][80];
  int tid = threadIdx.x;
  for (int i = tid; i < 10240; i += 256) {
    int u = i / 80, t = i - u * 80;
    int k = t % 20, q = t / 20;
    int ang = k + ((q >= 2) ? 1 : 0);
    int p = (u * ang) & 127;
    float a = (float)p * THETA;
    raw[u][t] = (q == 0 || q == 3) ? cosf(a) : sinf(a);
  }
  __syncthreads();
  float g[9]; gauss9(g);
  for (int i = tid; i < 10240; i += 256) {
    int u = i / 80, t = i - u * 80;
    int q = t / 20;
    float acc = 0.f;
#pragma unroll
    for (int tp = 0; tp < 9; ++tp) {
      int uc = u - 4 + tp; uc = uc < 0 ? 0 : (uc > 127 ? 127 : uc);
      acc += g[tp] * raw[uc][t];
    }
    Lg[t * 128 + u] = (q == 0) ? acc : -acc;
  }
  for (int i = tid; i < 10240; i += 256) {
    int t = i >> 7, v = i & 127;
    int k = t % 20, q = t / 20;
    int qs = (q == 2) ? 3 : ((q == 3) ? 2 : q);
    int src = k + 20 * qs;
    bool keep = (v <= 32) || (v >= 96);
    float acc = 0.f;
#pragma unroll
    for (int tp = 0; tp < 9; ++tp) {
      int vc = v - 4 + tp; vc = vc < 0 ? 0 : (vc > 127 ? 127 : vc);
      acc += g[tp] * raw[vc][src];
    }
    RBg[t * 128 + v] = keep ? acc : 0.f;
  }
}

// ---- k5b: per (b,o): Rs = O*RB (LDS), Y = L*Rs (8x8 register tile), store.
__global__ void __launch_bounds__(256) k5b_final(const float* __restrict__ O,
                                                 const float* __restrict__ Lg,
                                                 const float* __restrict__ RBg,
                                                 float* __restrict__ out) {
  __shared__ float Os[400];
  __shared__ float Rs[80][128];
  int bo = blockIdx.x, tid = threadIdx.x;
  for (int t = tid; t < 400; t += 256) Os[t] = O[bo * 400 + t];
  __syncthreads();
  // Rs[k+20q][v] = sum_k2 O[k][k2] * RB[k2+20q][v]
  for (int task = tid; task < 2560; task += 256) {
    int t = task >> 5, vg = task & 31;
    int v0 = vg * 4;
    int k = t % 20, q = t / 20;
    float4 acc = make_float4(0.f, 0.f, 0.f, 0.f);
#pragma unroll
    for (int k2 = 0; k2 < 20; ++k2) {
      float ov = Os[k * 20 + k2];
      float4 rb = *(const float4*)(RBg + ((q * 20 + k2) << 7) + v0);
      acc.x += ov * rb.x; acc.y += ov * rb.y; acc.z += ov * rb.z; acc.w += ov * rb.w;
    }
    *(float4*)&Rs[t][v0] = acc;
  }
  __syncthreads();
  int ug = tid >> 4, vg = tid & 15;
  int u0 = ug * 8, v0 = vg * 8;
  float acc[8][8];
#pragma unroll
  for (int i = 0; i < 8; ++i)
#pragma unroll
    for (int j = 0; j < 8; ++j) acc[i][j] = 0.f;
  for (int t = 0; t < 80; ++t) {
    float4 a0 = *(const float4*)(Lg + t * 128 + u0);
    float4 a1 = *(const float4*)(Lg + t * 128 + u0 + 4);
    float4 b0 = *(const float4*)&Rs[t][v0];
    float4 b1 = *(const float4*)&Rs[t][v0 + 4];
    float av[8] = {a0.x, a0.y, a0.z, a0.w, a1.x, a1.y, a1.z, a1.w};
    float bv[8] = {b0.x, b0.y, b0.z, b0.w, b1.x, b1.y, b1.z, b1.w};
#pragma unroll
    for (int i = 0; i < 8; ++i)
#pragma unroll
      for (int j = 0; j < 8; ++j) acc[i][j] += av[i] * bv[j];
  }
  long base = (long)bo * 16384;
#pragma unroll
  for (int i = 0; i < 8; ++i) {
    float4 s0 = make_float4(acc[i][0], acc[i][1], acc[i][2], acc[i][3]);
    float4 s1 = make_float4(acc[i][4], acc[i][5], acc[i][6], acc[i][7]);
    *(float4*)&out[base + (u0 + i) * 128 + v0] = s0;
    *(float4*)&out[base + (u0 + i) * 128 + v0 + 4] = s1;
  }
}

extern "C" void kernel_launch(void* const* d_in, const int* in_sizes, int n_in,
                              void* d_out, int out_size, void* d_ws, size_t ws_size,
                              hipStream_t stream) {
  const float* x = (const float*)d_in[0];    // (16,64,128,128)
  const float* w1 = (const float*)d_in[1];   // (64,64,20,20)
  float* out = (float*)d_out;                // (16,64,128,128)
  float* ws = (float*)d_ws;

  float* Wp = ws;                  // 1,638,400
  float* Wm = Wp + 1638400;        // 1,638,400
  float* Pw = Wm + 1638400;        // 5,242,880
  float* X1 = Pw + 5242880;        // 409,600
  float* X1b = X1 + 409600;        // 409,600
  float* O = X1b + 409600;         // 409,600
  float* Lg = O + 409600;          // 10,240
  float* RBg = Lg + 10240;         // 10,240  (total ~39 MB)

  hipLaunchKernelGGL(k0_weights, dim3(6400), dim3(256), 0, stream, w1, Wp, Wm);
  hipLaunchKernelGGL(k1_rows, dim3(2048), dim3(192), 0, stream, x, Pw);
  hipLaunchKernelGGL(k2_modes, dim3(1024), dim3(256), 0, stream, Pw, X1);
  hipLaunchKernelGGL(k2b_blurB, dim3(1600), dim3(256), 0, stream, X1, X1b);
  hipLaunchKernelGGL(k3_mix, dim3(400), dim3(256), 0, stream, X1b, Wp, Wm, O);
  hipLaunchKernelGGL(kinit, dim3(1), dim3(256), 0, stream, Lg, RBg);
  hipLaunchKernelGGL(k5b_final, dim3(1024), dim3(256), 0, stream, O, Lg, RBg, out);
}

// Round 3
// 348.229 us; speedup vs baseline: 1.5992x; 1.0365x over previous
//
#include <hip/hip_runtime.h>

// SpectralConv2d DHT spectral conv, B=16, Cin=Cout=64, H=W=128, modes 20x20.
// All stages linear; blurs folded into bases/weights. Rank-4 identity both ways:
//   fwd:  X(k1,k2) = sum_n1 [cos(th k1 n1) Pc - sin(th k1 n1) Ps
//                            - sin(th k1(n1+1)) Pc1 - cos(th k1(n1+1)) Ps1]
//   inv:  y(u,v)   = sum O[k1,k2][cos(th(u k1+v k2)) - sin(th(u(k1+1)+v(k2+1)))]
// Kernels:
//  kinit(3 blocks): Lg/RBg (inverse bases, blur-u/blur-v+mask folded),
//                   Tg (fwd row basis 128x40), Lf2g (fwd combine basis 20x512)
//  k0:  Wp/Wm = 0.5*(w1 +/- w1(-k))/16384, pre-blurred over Cout
//  k1:  Pw[r][col] = sum_n2 x[r][n2]*Tg[n2][col], col = k2 + 20*part
//  k2:  per (b,c): rotation -> Pm2[20][512], X1[m][bc] = Lf2g(20x512) . Pm2
//  k2b: blur X1 over batch axis
//  k3:  O[b,o,m] = sum_c X1b*Wp + X1b(-m)*Wm
//  k5b: per (b,o): Rs = O*RBg (LDS), Y = Lg*Rs, store

#define TWO_PI 6.283185307179586f
#define THETA (TWO_PI / 128.0f)

__device__ __forceinline__ void gauss9(float* g) {
  float s = 0.f;
#pragma unroll
  for (int t = 0; t < 9; ++t) { float d = (float)(t - 4); g[t] = expf(-0.5f * d * d); s += g[t]; }
  float inv = 1.f / s;
#pragma unroll
  for (int t = 0; t < 9; ++t) g[t] *= inv;
}

// ---- kinit: 3 blocks. b0: Lg+RBg (inverse), b1: Tg (fwd rows), b2: Lf2g (fwd combine)
__global__ void kinit(float* __restrict__ Lg, float* __restrict__ RBg,
                      float* __restrict__ Tg, float* __restrict__ Lf2g) {
  __shared__ float raw[128][80];
  int tid = threadIdx.x;
  int blk = blockIdx.x;
  if (blk == 1) {
    for (int i = tid; i < 5120; i += 256) {
      int n2 = i / 40, col = i - n2 * 40;
      int k2 = (col < 20) ? col : col - 20;
      float a = (float)((k2 * n2) & 127) * THETA;
      Tg[i] = (col < 20) ? cosf(a) : sinf(a);
    }
    return;
  }
  if (blk == 2) {
    for (int i = tid; i < 10240; i += 256) {
      int k1 = i >> 9, t = i & 511;
      int q = t >> 7, n1 = t & 127;
      int nn = n1 + ((q >= 2) ? 1 : 0);
      float a = (float)((k1 * nn) & 127) * THETA;
      float v;
      if (q == 0) v = cosf(a);
      else if (q == 1) v = -sinf(a);
      else if (q == 2) v = -sinf(a);
      else v = -cosf(a);
      Lf2g[i] = v;
    }
    return;
  }
  // block 0: inverse bases
  for (int i = tid; i < 10240; i += 256) {
    int u = i / 80, t = i - u * 80;
    int k = t % 20, q = t / 20;
    int ang = k + ((q >= 2) ? 1 : 0);
    int p = (u * ang) & 127;
    float a = (float)p * THETA;
    raw[u][t] = (q == 0 || q == 3) ? cosf(a) : sinf(a);
  }
  __syncthreads();
  float g[9]; gauss9(g);
  for (int i = tid; i < 10240; i += 256) {
    int u = i / 80, t = i - u * 80;
    int q = t / 20;
    float acc = 0.f;
#pragma unroll
    for (int tp = 0; tp < 9; ++tp) {
      int uc = u - 4 + tp; uc = uc < 0 ? 0 : (uc > 127 ? 127 : uc);
      acc += g[tp] * raw[uc][t];
    }
    Lg[t * 128 + u] = (q == 0) ? acc : -acc;
  }
  for (int i = tid; i < 10240; i += 256) {
    int t = i >> 7, v = i & 127;
    int k = t % 20, q = t / 20;
    int qs = (q == 2) ? 3 : ((q == 3) ? 2 : q);
    int src = k + 20 * qs;
    bool keep = (v <= 32) || (v >= 96);
    float acc = 0.f;
#pragma unroll
    for (int tp = 0; tp < 9; ++tp) {
      int vc = v - 4 + tp; vc = vc < 0 ? 0 : (vc > 127 ? 127 : vc);
      acc += g[tp] * raw[vc][src];
    }
    RBg[t * 128 + v] = keep ? acc : 0.f;
  }
}

// ---- k0: weight prep: Wp/Wm[(m*64+c)*64+o], blurred over o, scaled 0.5/16384
__global__ void k0_weights(const float* __restrict__ w1, float* __restrict__ Wp,
                           float* __restrict__ Wm) {
  int idx = blockIdx.x * 256 + threadIdx.x;
  if (idx >= 400 * 64 * 64) return;
  int o = idx & 63, c = (idx >> 6) & 63, m = idx >> 12;
  int i = m / 20, j = m - i * 20;
  int ni = (20 - i) % 20, nj = (20 - j) % 20;
  float g[9]; gauss9(g);
  float s = 0.f, d = 0.f;
#pragma unroll
  for (int t = 0; t < 9; ++t) {
    int oc = o - 4 + t; oc = oc < 0 ? 0 : (oc > 63 ? 63 : oc);
    float a = w1[((c * 64 + oc) * 20 + i) * 20 + j];
    float b = w1[((c * 64 + oc) * 20 + ni) * 20 + nj];
    s += g[t] * (a + b);
    d += g[t] * (a - b);
  }
  const float sc = 0.5f / 16384.0f;
  Wp[(m * 64 + c) * 64 + o] = s * sc;
  Wm[(m * 64 + c) * 64 + o] = d * sc;
}

// ---- k1 v4: Pw[131072 rows][40] = x[rows][128] * Tg[128][40]; 64 rows/block.
// LDS = xs only (35 KB -> 4 blocks/CU); Tg via L1 (20 KB, shared by all blocks).
__global__ void k1_rows(const float* __restrict__ x, const float* __restrict__ Tg,
                        float* __restrict__ Pw) {
  __shared__ float xs[128][68];   // [n2][r], col-major, pad 68 for b128 align
  int tid = threadIdx.x;
  long row0 = (long)blockIdx.x * 64;
  for (int t = tid; t < 2048; t += 192) {
    int r = t >> 5, c4 = t & 31;
    float4 v = *(const float4*)(x + (row0 + r) * 128 + c4 * 4);
    xs[c4 * 4 + 0][r] = v.x;
    xs[c4 * 4 + 1][r] = v.y;
    xs[c4 * 4 + 2][r] = v.z;
    xs[c4 * 4 + 3][r] = v.w;
  }
  __syncthreads();
  if (tid >= 160) return;
  int rg = tid / 10, cg = tid - rg * 10;
  int r0 = rg * 4, c0 = cg * 4;
  float acc[4][4];
#pragma unroll
  for (int i = 0; i < 4; ++i)
#pragma unroll
    for (int j = 0; j < 4; ++j) acc[i][j] = 0.f;
  for (int n2 = 0; n2 < 128; ++n2) {
    float4 xv = *(const float4*)&xs[n2][r0];
    float4 tv = *(const float4*)(Tg + n2 * 40 + c0);
    float xr[4] = {xv.x, xv.y, xv.z, xv.w};
    float tr[4] = {tv.x, tv.y, tv.z, tv.w};
#pragma unroll
    for (int i = 0; i < 4; ++i)
#pragma unroll
      for (int j = 0; j < 4; ++j) acc[i][j] += xr[i] * tr[j];
  }
#pragma unroll
  for (int i = 0; i < 4; ++i) {
    float4 st = make_float4(acc[i][0], acc[i][1], acc[i][2], acc[i][3]);
    *(float4*)&Pw[(row0 + r0 + i) * 40 + c0] = st;
  }
}

// ---- k2 v2: per (b,c): build Pm2[20][512] (rotation for q=2,3), then
// X1[(k1,k2)][bc] = sum_t Lf2g[k1][t] * Pm2[k2][t]  (2x2 register tiles)
__global__ void k2_modes(const float* __restrict__ Pw, const float* __restrict__ Lf2g,
                         float* __restrict__ X1) {
  __shared__ float Pm2[20][520];   // row stride 520 (16B-aligned)
  __shared__ float ct[128];
  int bc = blockIdx.x, tid = threadIdx.x;
  if (tid < 128) ct[tid] = cosf(THETA * (float)tid);
  const float4* src = (const float4*)(Pw + (long)bc * 5120);
  for (int t = tid; t < 1280; t += 256) {
    float4 v = src[t];
    int base = t * 4;
    int n1 = base / 40, col = base - 40 * n1;
    float vv[4] = {v.x, v.y, v.z, v.w};
#pragma unroll
    for (int j = 0; j < 4; ++j) {
      int cc = col + j;
      int k2 = (cc < 20) ? cc : cc - 20;
      int part = (cc < 20) ? 0 : 1;
      Pm2[k2][part * 128 + n1] = vv[j];
    }
  }
  __syncthreads();
  for (int t = tid; t < 2560; t += 256) {
    int k2 = t >> 7, n1 = t & 127;
    float pc = Pm2[k2][n1], ps = Pm2[k2][128 + n1];
    float ck = ct[k2], sk = ct[(k2 + 96) & 127];   // sin(th k2)
    Pm2[k2][256 + n1] = ck * pc - sk * ps;         // Pc1
    Pm2[k2][384 + n1] = sk * pc + ck * ps;         // Ps1
  }
  __syncthreads();
  if (tid >= 100) return;
  int k1 = (tid / 10) * 2, k2 = (tid % 10) * 2;
  float a00 = 0.f, a01 = 0.f, a10 = 0.f, a11 = 0.f;
  for (int t = 0; t < 512; t += 4) {
    float4 l0 = *(const float4*)(Lf2g + k1 * 512 + t);
    float4 l1 = *(const float4*)(Lf2g + (k1 + 1) * 512 + t);
    float4 p0 = *(const float4*)&Pm2[k2][t];
    float4 p1 = *(const float4*)&Pm2[k2 + 1][t];
    a00 += l0.x * p0.x + l0.y * p0.y + l0.z * p0.z + l0.w * p0.w;
    a01 += l0.x * p1.x + l0.y * p1.y + l0.z * p1.z + l0.w * p1.w;
    a10 += l1.x * p0.x + l1.y * p0.y + l1.z * p0.z + l1.w * p0.w;
    a11 += l1.x * p1.x + l1.y * p1.y + l1.z * p1.z + l1.w * p1.w;
  }
  X1[(k1 * 20 + k2) * 1024 + bc] = a00;
  X1[(k1 * 20 + k2 + 1) * 1024 + bc] = a01;
  X1[((k1 + 1) * 20 + k2) * 1024 + bc] = a10;
  X1[((k1 + 1) * 20 + k2 + 1) * 1024 + bc] = a11;
}

// ---- k2b: blur over batch axis (16, clamp)
__global__ void k2b_blurB(const float* __restrict__ X1, float* __restrict__ X1b) {
  int idx = blockIdx.x * 256 + threadIdx.x;
  if (idx >= 400 * 16 * 64) return;
  int c = idx & 63, b = (idx >> 6) & 15, m = idx >> 10;
  float g[9]; gauss9(g);
  float acc = 0.f;
#pragma unroll
  for (int t = 0; t < 9; ++t) {
    int bb = b - 4 + t; bb = bb < 0 ? 0 : (bb > 15 ? 15 : bb);
    acc += g[t] * X1[m * 1024 + bb * 64 + c];
  }
  X1b[idx] = acc;
}

// ---- k3: one block (256 thr) per mode m; O[(b*64+o)*400 + m]
__global__ void k3_mix(const float* __restrict__ X1b, const float* __restrict__ Wp,
                       const float* __restrict__ Wm, float* __restrict__ O) {
  __shared__ float Xa[1024], Xn[1024];
  int m = blockIdx.x, tid = threadIdx.x;
  int i = m / 20, j = m - i * 20;
  int nm = ((20 - i) % 20) * 20 + ((20 - j) % 20);
  for (int t = tid; t < 1024; t += 256) {
    Xa[t] = X1b[m * 1024 + t];
    Xn[t] = X1b[nm * 1024 + t];
  }
  __syncthreads();
  int o = tid & 63, b0 = tid >> 6;
  float acc[4] = {0.f, 0.f, 0.f, 0.f};
  for (int c = 0; c < 64; ++c) {
    float wp = Wp[(m * 64 + c) * 64 + o];
    float wm = Wm[(m * 64 + c) * 64 + o];
#pragma unroll
    for (int q = 0; q < 4; ++q) {
      int b = b0 + q * 4;
      acc[q] += Xa[b * 64 + c] * wp + Xn[b * 64 + c] * wm;
    }
  }
#pragma unroll
  for (int q = 0; q < 4; ++q) {
    int b = b0 + q * 4;
    O[(b * 64 + o) * 400 + m] = acc[q];
  }
}

// ---- k5b: per (b,o): Rs = O*RBg (LDS), Y = Lg*Rs (8x8 register tile), store.
__global__ void __launch_bounds__(256) k5b_final(const float* __restrict__ O,
                                                 const float* __restrict__ Lg,
                                                 const float* __restrict__ RBg,
                                                 float* __restrict__ out) {
  __shared__ float Os[400];
  __shared__ float Rs[80][128];
  int bo = blockIdx.x, tid = threadIdx.x;
  for (int t = tid; t < 400; t += 256) Os[t] = O[bo * 400 + t];
  __syncthreads();
  for (int task = tid; task < 2560; task += 256) {
    int t = task >> 5, vg = task & 31;
    int v0 = vg * 4;
    int k = t % 20, q = t / 20;
    float4 acc = make_float4(0.f, 0.f, 0.f, 0.f);
#pragma unroll
    for (int k2 = 0; k2 < 20; ++k2) {
      float ov = Os[k * 20 + k2];
      float4 rb = *(const float4*)(RBg + ((q * 20 + k2) << 7) + v0);
      acc.x += ov * rb.x; acc.y += ov * rb.y; acc.z += ov * rb.z; acc.w += ov * rb.w;
    }
    *(float4*)&Rs[t][v0] = acc;
  }
  __syncthreads();
  int ug = tid >> 4, vg = tid & 15;
  int u0 = ug * 8, v0 = vg * 8;
  float acc[8][8];
#pragma unroll
  for (int i = 0; i < 8; ++i)
#pragma unroll
    for (int j = 0; j < 8; ++j) acc[i][j] = 0.f;
  for (int t = 0; t < 80; ++t) {
    float4 a0 = *(const float4*)(Lg + t * 128 + u0);
    float4 a1 = *(const float4*)(Lg + t * 128 + u0 + 4);
    float4 b0 = *(const float4*)&Rs[t][v0];
    float4 b1 = *(const float4*)&Rs[t][v0 + 4];
    float av[8] = {a0.x, a0.y, a0.z, a0.w, a1.x, a1.y, a1.z, a1.w};
    float bv[8] = {b0.x, b0.y, b0.z, b0.w, b1.x, b1.y, b1.z, b1.w};
#pragma unroll
    for (int i = 0; i < 8; ++i)
#pragma unroll
      for (int j = 0; j < 8; ++j) acc[i][j] += av[i] * bv[j];
  }
  long base = (long)bo * 16384;
#pragma unroll
  for (int i = 0; i < 8; ++i) {
    float4 s0 = make_float4(acc[i][0], acc[i][1], acc[i][2], acc[i][3]);
    float4 s1 = make_float4(acc[i][4], acc[i][5], acc[i][6], acc[i][7]);
    *(float4*)&out[base + (u0 + i) * 128 + v0] = s0;
    *(float4*)&out[base + (u0 + i) * 128 + v0 + 4] = s1;
  }
}

extern "C" void kernel_launch(void* const* d_in, const int* in_sizes, int n_in,
                              void* d_out, int out_size, void* d_ws, size_t ws_size,
                              hipStream_t stream) {
  const float* x = (const float*)d_in[0];    // (16,64,128,128)
  const float* w1 = (const float*)d_in[1];   // (64,64,20,20)
  float* out = (float*)d_out;                // (16,64,128,128)
  float* ws = (float*)d_ws;

  float* Wp = ws;                  // 1,638,400
  float* Wm = Wp + 1638400;        // 1,638,400
  float* Pw = Wm + 1638400;        // 5,242,880
  float* X1 = Pw + 5242880;        // 409,600
  float* X1b = X1 + 409600;        // 409,600
  float* O = X1b + 409600;         // 409,600
  float* Lg = O + 409600;          // 10,240
  float* RBg = Lg + 10240;         // 10,240
  float* Tg = RBg + 10240;         // 5,120
  float* Lf2g = Tg + 5120;         // 10,240  (total ~39 MB)

  hipLaunchKernelGGL(kinit, dim3(3), dim3(256), 0, stream, Lg, RBg, Tg, Lf2g);
  hipLaunchKernelGGL(k0_weights, dim3(6400), dim3(256), 0, stream, w1, Wp, Wm);
  hipLaunchKernelGGL(k1_rows, dim3(2048), dim3(192), 0, stream, x, Tg, Pw);
  hipLaunchKernelGGL(k2_modes, dim3(1024), dim3(256), 0, stream, Pw, Lf2g, X1);
  hipLaunchKernelGGL(k2b_blurB, dim3(1600), dim3(256), 0, stream, X1, X1b);
  hipLaunchKernelGGL(k3_mix, dim3(400), dim3(256), 0, stream, X1b, Wp, Wm, O);
  hipLaunchKernelGGL(k5b_final, dim3(1024), dim3(256), 0, stream, O, Lg, RBg, out);
}

// Round 4
// 266.788 us; speedup vs baseline: 2.0874x; 1.3053x over previous
//
#include <hip/hip_runtime.h>

// SpectralConv2d DHT spectral conv, B=16, Cin=Cout=64, H=W=128, modes 20x20.
// All stages linear; blurs folded into bases/weights.
//   fwd:  X(k1,k2) = sum_n1 [cos(th k1 n1) Pc - sin(th k1 n1) Ps
//                            - sin(th k1(n1+1)) Pc1 - cos(th k1(n1+1)) Ps1]
//   inv (rank-42): y(u,v) = sum_{A=0..20} cosb(u,A)*RsC[A][v] + sinb(u,A)*RsS[A][v]
//     RsC[A] = sum_k2 O[A][k2] Bc[k2]   - sum_k2 O[A-1][k2] Bs[k2+1]
//     RsS[A] = -sum_k2 O[A][k2] Bs[k2]  - sum_k2 O[A-1][k2] Bc[k2+1]
//   (Bc/Bs = blur_v+mask basis; cosb/sinb = blur_u basis)
// Kernels:
//  kinit(3 blocks): L2g/RB2g (42x128 inverse bases), Tg (128x40), Lf2g (20x512)
//  k0a: blur w1 over Cout + transpose -> wbT[c][m][o] (coalesced both ways)
//  k0b: Wp/Wm[m][c][o] = sc*(wbT[c][m][o] +/- wbT[c][nm][o])
//  k1:  Pw[r][col] = sum_n2 x[r][n2]*Tg[n2][col]
//  k2:  per (b,c): rotation -> Pm2[20][512], X1[m][bc] = Lf2g . Pm2
//  k2b: blur X1 over batch; k3: channel mix -> O[b,o,m]
//  k5b: per (b,o): Rs2[42][128] in LDS, Y = L2 * Rs2, conflict-free reads

#define TWO_PI 6.283185307179586f
#define THETA (TWO_PI / 128.0f)

__device__ __forceinline__ void gauss9(float* g) {
  float s = 0.f;
#pragma unroll
  for (int t = 0; t < 9; ++t) { float d = (float)(t - 4); g[t] = expf(-0.5f * d * d); s += g[t]; }
  float inv = 1.f / s;
#pragma unroll
  for (int t = 0; t < 9; ++t) g[t] *= inv;
}

// ---- kinit: b0: L2g+RB2g (42x128 each), b1: Tg, b2: Lf2g
__global__ void kinit(float* __restrict__ L2g, float* __restrict__ RB2g,
                      float* __restrict__ Tg, float* __restrict__ Lf2g) {
  __shared__ float raw[128][44];
  int tid = threadIdx.x;
  int blk = blockIdx.x;
  if (blk == 1) {
    for (int i = tid; i < 5120; i += 256) {
      int n2 = i / 40, col = i - n2 * 40;
      int k2 = (col < 20) ? col : col - 20;
      float a = (float)((k2 * n2) & 127) * THETA;
      Tg[i] = (col < 20) ? cosf(a) : sinf(a);
    }
    return;
  }
  if (blk == 2) {
    for (int i = tid; i < 10240; i += 256) {
      int k1 = i >> 9, t = i & 511;
      int q = t >> 7, n1 = t & 127;
      int nn = n1 + ((q >= 2) ? 1 : 0);
      float a = (float)((k1 * nn) & 127) * THETA;
      float v;
      if (q == 0) v = cosf(a);
      else if (q == 1) v = -sinf(a);
      else if (q == 2) v = -sinf(a);
      else v = -cosf(a);
      Lf2g[i] = v;
    }
    return;
  }
  // block 0: rank-42 bases. rows 0..20 = cos(th u A), 21..41 = sin(th u A)
  for (int i = tid; i < 5376; i += 256) {
    int u = i / 42, t = i - u * 42;
    int A = (t < 21) ? t : t - 21;
    float a = (float)((u * A) & 127) * THETA;
    raw[u][t] = (t < 21) ? cosf(a) : sinf(a);
  }
  __syncthreads();
  float g[9]; gauss9(g);
  for (int i = tid; i < 5376; i += 256) {
    int u = i / 42, t = i - u * 42;
    float acc = 0.f;
#pragma unroll
    for (int tp = 0; tp < 9; ++tp) {
      int uc = u - 4 + tp; uc = uc < 0 ? 0 : (uc > 127 ? 127 : uc);
      acc += g[tp] * raw[uc][t];
    }
    L2g[t * 128 + u] = acc;
    bool keep = (u <= 32) || (u >= 96);
    RB2g[t * 128 + u] = keep ? acc : 0.f;
  }
}

// ---- k0a: blur w1 over Cout + transpose: wbT[(c*400+m)*64+o]
__global__ void k0a_blurT(const float* __restrict__ w1, float* __restrict__ wbT) {
  __shared__ float tile[64][69];
  int c = blockIdx.x / 7, chunk = blockIdx.x % 7;
  int m0 = chunk * 64;
  int mw = 400 - m0; if (mw > 64) mw = 64;
  int tid = threadIdx.x;
  for (int t = tid; t < 4096; t += 256) {
    int o = t >> 6, mm = t & 63;
    tile[o][mm] = (mm < mw) ? w1[(c * 64 + o) * 400 + m0 + mm] : 0.f;
  }
  __syncthreads();
  float g[9]; gauss9(g);
  for (int t = tid; t < 4096; t += 256) {
    int mm = t >> 6, o = t & 63;
    if (mm >= mw) continue;
    float acc = 0.f;
#pragma unroll
    for (int tp = 0; tp < 9; ++tp) {
      int oc = o - 4 + tp; oc = oc < 0 ? 0 : (oc > 63 ? 63 : oc);
      acc += g[tp] * tile[oc][mm];
    }
    wbT[(c * 400 + m0 + mm) * 64 + o] = acc;
  }
}

// ---- k0b: Wp/Wm[(m*64+c)*64+o] = sc*(wbT[c][m][o] +/- wbT[c][nm][o])
__global__ void k0b_combine(const float* __restrict__ wbT, float* __restrict__ Wp,
                            float* __restrict__ Wm) {
  int m = blockIdx.x;
  int i = m / 20, j = m - i * 20;
  int nm = ((20 - i) % 20) * 20 + ((20 - j) % 20);
  int tid = threadIdx.x;
  const float sc = 0.5f / 16384.0f;
  for (int t = tid; t < 4096; t += 256) {
    int c = t >> 6, o = t & 63;
    float a = wbT[(c * 400 + m) * 64 + o];
    float b = wbT[(c * 400 + nm) * 64 + o];
    Wp[(m * 64 + c) * 64 + o] = (a + b) * sc;
    Wm[(m * 64 + c) * 64 + o] = (a - b) * sc;
  }
}

// ---- k1: Pw[131072 rows][40] = x[rows][128] * Tg[128][40]; 64 rows/block.
__global__ void k1_rows(const float* __restrict__ x, const float* __restrict__ Tg,
                        float* __restrict__ Pw) {
  __shared__ float xs[128][68];
  int tid = threadIdx.x;
  long row0 = (long)blockIdx.x * 64;
  for (int t = tid; t < 2048; t += 192) {
    int r = t >> 5, c4 = t & 31;
    float4 v = *(const float4*)(x + (row0 + r) * 128 + c4 * 4);
    xs[c4 * 4 + 0][r] = v.x;
    xs[c4 * 4 + 1][r] = v.y;
    xs[c4 * 4 + 2][r] = v.z;
    xs[c4 * 4 + 3][r] = v.w;
  }
  __syncthreads();
  if (tid >= 160) return;
  int rg = tid / 10, cg = tid - rg * 10;
  int r0 = rg * 4, c0 = cg * 4;
  float acc[4][4];
#pragma unroll
  for (int i = 0; i < 4; ++i)
#pragma unroll
    for (int j = 0; j < 4; ++j) acc[i][j] = 0.f;
  for (int n2 = 0; n2 < 128; ++n2) {
    float4 xv = *(const float4*)&xs[n2][r0];
    float4 tv = *(const float4*)(Tg + n2 * 40 + c0);
    float xr[4] = {xv.x, xv.y, xv.z, xv.w};
    float tr[4] = {tv.x, tv.y, tv.z, tv.w};
#pragma unroll
    for (int i = 0; i < 4; ++i)
#pragma unroll
      for (int j = 0; j < 4; ++j) acc[i][j] += xr[i] * tr[j];
  }
#pragma unroll
  for (int i = 0; i < 4; ++i) {
    float4 st = make_float4(acc[i][0], acc[i][1], acc[i][2], acc[i][3]);
    *(float4*)&Pw[(row0 + r0 + i) * 40 + c0] = st;
  }
}

// ---- k2: per (b,c): Pm2[20][512] (with rotation), X1[m][bc] = Lf2g . Pm2
__global__ void k2_modes(const float* __restrict__ Pw, const float* __restrict__ Lf2g,
                         float* __restrict__ X1) {
  __shared__ float Pm2[20][520];
  __shared__ float ct[128];
  int bc = blockIdx.x, tid = threadIdx.x;
  if (tid < 128) ct[tid] = cosf(THETA * (float)tid);
  const float4* src = (const float4*)(Pw + (long)bc * 5120);
  for (int t = tid; t < 1280; t += 256) {
    float4 v = src[t];
    int base = t * 4;
    int n1 = base / 40, col = base - 40 * n1;
    float vv[4] = {v.x, v.y, v.z, v.w};
#pragma unroll
    for (int j = 0; j < 4; ++j) {
      int cc = col + j;
      int k2 = (cc < 20) ? cc : cc - 20;
      int part = (cc < 20) ? 0 : 1;
      Pm2[k2][part * 128 + n1] = vv[j];
    }
  }
  __syncthreads();
  for (int t = tid; t < 2560; t += 256) {
    int k2 = t >> 7, n1 = t & 127;
    float pc = Pm2[k2][n1], ps = Pm2[k2][128 + n1];
    float ck = ct[k2], sk = ct[(k2 + 96) & 127];
    Pm2[k2][256 + n1] = ck * pc - sk * ps;
    Pm2[k2][384 + n1] = sk * pc + ck * ps;
  }
  __syncthreads();
  if (tid >= 100) return;
  int k1 = (tid / 10) * 2, k2 = (tid % 10) * 2;
  float a00 = 0.f, a01 = 0.f, a10 = 0.f, a11 = 0.f;
  for (int t = 0; t < 512; t += 4) {
    float4 l0 = *(const float4*)(Lf2g + k1 * 512 + t);
    float4 l1 = *(const float4*)(Lf2g + (k1 + 1) * 512 + t);
    float4 p0 = *(const float4*)&Pm2[k2][t];
    float4 p1 = *(const float4*)&Pm2[k2 + 1][t];
    a00 += l0.x * p0.x + l0.y * p0.y + l0.z * p0.z + l0.w * p0.w;
    a01 += l0.x * p1.x + l0.y * p1.y + l0.z * p1.z + l0.w * p1.w;
    a10 += l1.x * p0.x + l1.y * p0.y + l1.z * p0.z + l1.w * p0.w;
    a11 += l1.x * p1.x + l1.y * p1.y + l1.z * p1.z + l1.w * p1.w;
  }
  X1[(k1 * 20 + k2) * 1024 + bc] = a00;
  X1[(k1 * 20 + k2 + 1) * 1024 + bc] = a01;
  X1[((k1 + 1) * 20 + k2) * 1024 + bc] = a10;
  X1[((k1 + 1) * 20 + k2 + 1) * 1024 + bc] = a11;
}

// ---- k2b: blur over batch axis (16, clamp)
__global__ void k2b_blurB(const float* __restrict__ X1, float* __restrict__ X1b) {
  int idx = blockIdx.x * 256 + threadIdx.x;
  if (idx >= 400 * 16 * 64) return;
  int c = idx & 63, b = (idx >> 6) & 15, m = idx >> 10;
  float g[9]; gauss9(g);
  float acc = 0.f;
#pragma unroll
  for (int t = 0; t < 9; ++t) {
    int bb = b - 4 + t; bb = bb < 0 ? 0 : (bb > 15 ? 15 : bb);
    acc += g[t] * X1[m * 1024 + bb * 64 + c];
  }
  X1b[idx] = acc;
}

// ---- k3: one block per mode m; O[(b*64+o)*400 + m]
__global__ void k3_mix(const float* __restrict__ X1b, const float* __restrict__ Wp,
                       const float* __restrict__ Wm, float* __restrict__ O) {
  __shared__ float Xa[1024], Xn[1024];
  int m = blockIdx.x, tid = threadIdx.x;
  int i = m / 20, j = m - i * 20;
  int nm = ((20 - i) % 20) * 20 + ((20 - j) % 20);
  for (int t = tid; t < 1024; t += 256) {
    Xa[t] = X1b[m * 1024 + t];
    Xn[t] = X1b[nm * 1024 + t];
  }
  __syncthreads();
  int o = tid & 63, b0 = tid >> 6;
  float acc[4] = {0.f, 0.f, 0.f, 0.f};
  for (int c = 0; c < 64; ++c) {
    float wp = Wp[(m * 64 + c) * 64 + o];
    float wm = Wm[(m * 64 + c) * 64 + o];
#pragma unroll
    for (int q = 0; q < 4; ++q) {
      int b = b0 + q * 4;
      acc[q] += Xa[b * 64 + c] * wp + Xn[b * 64 + c] * wm;
    }
  }
#pragma unroll
  for (int q = 0; q < 4; ++q) {
    int b = b0 + q * 4;
    O[(b * 64 + o) * 400 + m] = acc[q];
  }
}

// ---- k5b: per (b,o): Rs2[42][128] (C rows 0..20, S rows 21..41), Y = L2 * Rs2
__global__ void __launch_bounds__(256) k5b_final(const float* __restrict__ O,
                                                 const float* __restrict__ L2g,
                                                 const float* __restrict__ RB2g,
                                                 float* __restrict__ out) {
  __shared__ float Os[400];
  __shared__ float Rs[42 * 128];
  int bo = blockIdx.x, tid = threadIdx.x;
  for (int t = tid; t < 400; t += 256) Os[t] = O[bo * 400 + t];
  __syncthreads();
  const float4* Bc4 = (const float4*)RB2g;             // rows 0..20
  const float4* Bs4 = (const float4*)(RB2g + 21 * 128);
  for (int task = tid; task < 1344; task += 256) {
    int r = task >> 5, vq = task & 31;
    bool isS = (r >= 21);
    int A = isS ? (r - 21) : r;
    float4 acc = make_float4(0.f, 0.f, 0.f, 0.f);
    if (A < 20) {
      const float4* Bm = isS ? Bs4 : Bc4;
      float sgn = isS ? -1.f : 1.f;
#pragma unroll
      for (int k2 = 0; k2 < 20; ++k2) {
        float ov = sgn * Os[A * 20 + k2];
        float4 b = Bm[k2 * 32 + vq];
        acc.x += ov * b.x; acc.y += ov * b.y; acc.z += ov * b.z; acc.w += ov * b.w;
      }
    }
    if (A >= 1) {
      const float4* Bm = isS ? Bc4 : Bs4;
#pragma unroll
      for (int k2 = 0; k2 < 20; ++k2) {
        float ov = Os[(A - 1) * 20 + k2];
        float4 b = Bm[(k2 + 1) * 32 + vq];
        acc.x -= ov * b.x; acc.y -= ov * b.y; acc.z -= ov * b.z; acc.w -= ov * b.w;
      }
    }
    *(float4*)&Rs[r * 128 + vq * 4] = acc;
  }
  __syncthreads();
  int ug = tid >> 4, vg = tid & 15;
  int u0 = ug * 8, v0 = vg * 4;   // v-cols: v0..v0+3 and 64+v0..64+v0+3
  float acc[8][8];
#pragma unroll
  for (int i = 0; i < 8; ++i)
#pragma unroll
    for (int j = 0; j < 8; ++j) acc[i][j] = 0.f;
  for (int r = 0; r < 42; ++r) {
    float4 a0 = *(const float4*)(L2g + r * 128 + u0);
    float4 a1 = *(const float4*)(L2g + r * 128 + u0 + 4);
    float4 b0 = *(const float4*)&Rs[r * 128 + v0];
    float4 b1 = *(const float4*)&Rs[r * 128 + 64 + v0];
    float av[8] = {a0.x, a0.y, a0.z, a0.w, a1.x, a1.y, a1.z, a1.w};
    float bv[8] = {b0.x, b0.y, b0.z, b0.w, b1.x, b1.y, b1.z, b1.w};
#pragma unroll
    for (int i = 0; i < 8; ++i)
#pragma unroll
      for (int j = 0; j < 8; ++j) acc[i][j] += av[i] * bv[j];
  }
  long base = (long)bo * 16384;
#pragma unroll
  for (int i = 0; i < 8; ++i) {
    float4 s0 = make_float4(acc[i][0], acc[i][1], acc[i][2], acc[i][3]);
    float4 s1 = make_float4(acc[i][4], acc[i][5], acc[i][6], acc[i][7]);
    *(float4*)&out[base + (u0 + i) * 128 + v0] = s0;
    *(float4*)&out[base + (u0 + i) * 128 + 64 + v0] = s1;
  }
}

extern "C" void kernel_launch(void* const* d_in, const int* in_sizes, int n_in,
                              void* d_out, int out_size, void* d_ws, size_t ws_size,
                              hipStream_t stream) {
  const float* x = (const float*)d_in[0];    // (16,64,128,128)
  const float* w1 = (const float*)d_in[1];   // (64,64,20,20)
  float* out = (float*)d_out;                // (16,64,128,128)
  float* ws = (float*)d_ws;

  float* Wp = ws;                  // 1,638,400
  float* Wm = Wp + 1638400;        // 1,638,400
  float* Pw = Wm + 1638400;        // 5,242,880
  float* X1 = Pw + 5242880;        // 409,600
  float* X1b = X1 + 409600;        // 409,600
  float* O = X1b + 409600;         // 409,600
  float* wbT = O + 409600;         // 1,638,400
  float* Tg = wbT + 1638400;       // 5,120
  float* Lf2g = Tg + 5120;         // 10,240
  float* L2g = Lf2g + 10240;       // 5,376
  float* RB2g = L2g + 5376;        // 5,376   (total ~45 MB)

  hipLaunchKernelGGL(kinit, dim3(3), dim3(256), 0, stream, L2g, RB2g, Tg, Lf2g);
  hipLaunchKernelGGL(k0a_blurT, dim3(448), dim3(256), 0, stream, w1, wbT);
  hipLaunchKernelGGL(k0b_combine, dim3(400), dim3(256), 0, stream, wbT, Wp, Wm);
  hipLaunchKernelGGL(k1_rows, dim3(2048), dim3(192), 0, stream, x, Tg, Pw);
  hipLaunchKernelGGL(k2_modes, dim3(1024), dim3(256), 0, stream, Pw, Lf2g, X1);
  hipLaunchKernelGGL(k2b_blurB, dim3(1600), dim3(256), 0, stream, X1, X1b);
  hipLaunchKernelGGL(k3_mix, dim3(400), dim3(256), 0, stream, X1b, Wp, Wm, O);
  hipLaunchKernelGGL(k5b_final, dim3(1024), dim3(256), 0, stream, O, L2g, RB2g, out);
}

// Round 5
// 263.174 us; speedup vs baseline: 2.1161x; 1.0137x over previous
//
#include <hip/hip_runtime.h>

// SpectralConv2d DHT spectral conv, B=16, Cin=Cout=64, H=W=128, modes 20x20.
// All stages linear; blurs folded into bases/weights.
//   fwd:  X(k1,k2) = sum_n1 [cos(th k1 n1) Pc - sin(th k1 n1) Ps
//                            - sin(th k1(n1+1)) Pc1 - cos(th k1(n1+1)) Ps1]
//   inv (rank-42): y(u,v) = sum_{A=0..20} cosb(u,A)*RsC[A][v] + sinb(u,A)*RsS[A][v]
// Kernels:
//  kinit(3 blocks): L2g/RB2g (42x128 inverse bases), Tg (128x40), Lf2g (20x512)
//  k0a: blur w1 over Cout + transpose -> wbT;  k0b: Wp/Wm combine
//  k1:  Pw[r][col] = sum_n2 x[r][n2]*Tg[n2][col]  (XOR-swizzled LDS, conflict-free)
//  k2:  per (b,c): rotation -> Pm2[20][524], X1[m][bc] = Lf2g . Pm2
//  k2b: blur X1 over batch; k3: channel mix -> O[b,o,m]
//  k5b: per (b,o): Rs2[42][128] in LDS, Y = L2 * Rs2

#define TWO_PI 6.283185307179586f
#define THETA (TWO_PI / 128.0f)

__device__ __forceinline__ void gauss9(float* g) {
  float s = 0.f;
#pragma unroll
  for (int t = 0; t < 9; ++t) { float d = (float)(t - 4); g[t] = expf(-0.5f * d * d); s += g[t]; }
  float inv = 1.f / s;
#pragma unroll
  for (int t = 0; t < 9; ++t) g[t] *= inv;
}

// ---- kinit: b0: L2g+RB2g (42x128 each), b1: Tg, b2: Lf2g
__global__ void kinit(float* __restrict__ L2g, float* __restrict__ RB2g,
                      float* __restrict__ Tg, float* __restrict__ Lf2g) {
  __shared__ float raw[128][44];
  int tid = threadIdx.x;
  int blk = blockIdx.x;
  if (blk == 1) {
    for (int i = tid; i < 5120; i += 256) {
      int n2 = i / 40, col = i - n2 * 40;
      int k2 = (col < 20) ? col : col - 20;
      float a = (float)((k2 * n2) & 127) * THETA;
      Tg[i] = (col < 20) ? cosf(a) : sinf(a);
    }
    return;
  }
  if (blk == 2) {
    for (int i = tid; i < 10240; i += 256) {
      int k1 = i >> 9, t = i & 511;
      int q = t >> 7, n1 = t & 127;
      int nn = n1 + ((q >= 2) ? 1 : 0);
      float a = (float)((k1 * nn) & 127) * THETA;
      float v;
      if (q == 0) v = cosf(a);
      else if (q == 1) v = -sinf(a);
      else if (q == 2) v = -sinf(a);
      else v = -cosf(a);
      Lf2g[i] = v;
    }
    return;
  }
  // block 0: rank-42 bases. rows 0..20 = cos(th u A), 21..41 = sin(th u A)
  for (int i = tid; i < 5376; i += 256) {
    int u = i / 42, t = i - u * 42;
    int A = (t < 21) ? t : t - 21;
    float a = (float)((u * A) & 127) * THETA;
    raw[u][t] = (t < 21) ? cosf(a) : sinf(a);
  }
  __syncthreads();
  float g[9]; gauss9(g);
  for (int i = tid; i < 5376; i += 256) {
    int u = i / 42, t = i - u * 42;
    float acc = 0.f;
#pragma unroll
    for (int tp = 0; tp < 9; ++tp) {
      int uc = u - 4 + tp; uc = uc < 0 ? 0 : (uc > 127 ? 127 : uc);
      acc += g[tp] * raw[uc][t];
    }
    L2g[t * 128 + u] = acc;
    bool keep = (u <= 32) || (u >= 96);
    RB2g[t * 128 + u] = keep ? acc : 0.f;
  }
}

// ---- k0a: blur w1 over Cout + transpose: wbT[(c*400+m)*64+o]
__global__ void k0a_blurT(const float* __restrict__ w1, float* __restrict__ wbT) {
  __shared__ float tile[64][69];
  int c = blockIdx.x / 7, chunk = blockIdx.x % 7;
  int m0 = chunk * 64;
  int mw = 400 - m0; if (mw > 64) mw = 64;
  int tid = threadIdx.x;
  for (int t = tid; t < 4096; t += 256) {
    int o = t >> 6, mm = t & 63;
    tile[o][mm] = (mm < mw) ? w1[(c * 64 + o) * 400 + m0 + mm] : 0.f;
  }
  __syncthreads();
  float g[9]; gauss9(g);
  for (int t = tid; t < 4096; t += 256) {
    int mm = t >> 6, o = t & 63;
    if (mm >= mw) continue;
    float acc = 0.f;
#pragma unroll
    for (int tp = 0; tp < 9; ++tp) {
      int oc = o - 4 + tp; oc = oc < 0 ? 0 : (oc > 63 ? 63 : oc);
      acc += g[tp] * tile[oc][mm];
    }
    wbT[(c * 400 + m0 + mm) * 64 + o] = acc;
  }
}

// ---- k0b: Wp/Wm[(m*64+c)*64+o] = sc*(wbT[c][m][o] +/- wbT[c][nm][o])
__global__ void k0b_combine(const float* __restrict__ wbT, float* __restrict__ Wp,
                            float* __restrict__ Wm) {
  int m = blockIdx.x;
  int i = m / 20, j = m - i * 20;
  int nm = ((20 - i) % 20) * 20 + ((20 - j) % 20);
  int tid = threadIdx.x;
  const float sc = 0.5f / 16384.0f;
  for (int t = tid; t < 4096; t += 256) {
    int c = t >> 6, o = t & 63;
    float a = wbT[(c * 400 + m) * 64 + o];
    float b = wbT[(c * 400 + nm) * 64 + o];
    Wp[(m * 64 + c) * 64 + o] = (a + b) * sc;
    Wm[(m * 64 + c) * 64 + o] = (a - b) * sc;
  }
}

// ---- k1 v5: Pw[131072 rows][40] = x[rows][128] * Tg[128][40]; 64 rows/block.
// XOR-swizzled transposed LDS: element (n2,r) at xs[n2][ ((r>>2)^(n2&15))*4 + (r&3) ].
// Staging: scalar loads (coalesced) + scalar stores (4-way max). Compute: b128, conflict-free.
__global__ void k1_rows(const float* __restrict__ x, const float* __restrict__ Tg,
                        float* __restrict__ Pw) {
  __shared__ float xs[128 * 64];
  int tid = threadIdx.x;
  long row0 = (long)blockIdx.x * 64;
  for (int t = tid; t < 8192; t += 192) {
    int n2 = t & 127, r = t >> 7;
    float v = x[(row0 + r) * 128 + n2];
    int col = (((r >> 2) ^ (n2 & 15)) << 2) + (r & 3);
    xs[n2 * 64 + col] = v;
  }
  __syncthreads();
  if (tid >= 160) return;
  int rg = tid / 10, cg = tid - rg * 10;
  int r0 = rg * 4, c0 = cg * 4;
  float acc[4][4];
#pragma unroll
  for (int i = 0; i < 4; ++i)
#pragma unroll
    for (int j = 0; j < 4; ++j) acc[i][j] = 0.f;
  for (int n2 = 0; n2 < 128; ++n2) {
    float4 xv = *(const float4*)&xs[n2 * 64 + ((rg ^ (n2 & 15)) << 2)];
    float4 tv = *(const float4*)(Tg + n2 * 40 + c0);
    float xr[4] = {xv.x, xv.y, xv.z, xv.w};
    float tr[4] = {tv.x, tv.y, tv.z, tv.w};
#pragma unroll
    for (int i = 0; i < 4; ++i)
#pragma unroll
      for (int j = 0; j < 4; ++j) acc[i][j] += xr[i] * tr[j];
  }
#pragma unroll
  for (int i = 0; i < 4; ++i) {
    float4 st = make_float4(acc[i][0], acc[i][1], acc[i][2], acc[i][3]);
    *(float4*)&Pw[(row0 + r0 + i) * 40 + c0] = st;
  }
}

// ---- k2: per (b,c): Pm2[20][524] (with rotation), X1[m][bc] = Lf2g . Pm2
__global__ void k2_modes(const float* __restrict__ Pw, const float* __restrict__ Lf2g,
                         float* __restrict__ X1) {
  __shared__ float Pm2[20][524];
  __shared__ float ct[128];
  int bc = blockIdx.x, tid = threadIdx.x;
  if (tid < 128) ct[tid] = cosf(THETA * (float)tid);
  const float4* src = (const float4*)(Pw + (long)bc * 5120);
  for (int t = tid; t < 1280; t += 256) {
    float4 v = src[t];
    int base = t * 4;
    int n1 = base / 40, col = base - 40 * n1;
    float vv[4] = {v.x, v.y, v.z, v.w};
#pragma unroll
    for (int j = 0; j < 4; ++j) {
      int cc = col + j;
      int k2 = (cc < 20) ? cc : cc - 20;
      int part = (cc < 20) ? 0 : 1;
      Pm2[k2][part * 128 + n1] = vv[j];
    }
  }
  __syncthreads();
  for (int t = tid; t < 2560; t += 256) {
    int k2 = t >> 7, n1 = t & 127;
    float pc = Pm2[k2][n1], ps = Pm2[k2][128 + n1];
    float ck = ct[k2], sk = ct[(k2 + 96) & 127];
    Pm2[k2][256 + n1] = ck * pc - sk * ps;
    Pm2[k2][384 + n1] = sk * pc + ck * ps;
  }
  __syncthreads();
  if (tid >= 100) return;
  int k1 = (tid / 10) * 2, k2 = (tid % 10) * 2;
  float a00 = 0.f, a01 = 0.f, a10 = 0.f, a11 = 0.f;
  for (int t = 0; t < 512; t += 4) {
    float4 l0 = *(const float4*)(Lf2g + k1 * 512 + t);
    float4 l1 = *(const float4*)(Lf2g + (k1 + 1) * 512 + t);
    float4 p0 = *(const float4*)&Pm2[k2][t];
    float4 p1 = *(const float4*)&Pm2[k2 + 1][t];
    a00 += l0.x * p0.x + l0.y * p0.y + l0.z * p0.z + l0.w * p0.w;
    a01 += l0.x * p1.x + l0.y * p1.y + l0.z * p1.z + l0.w * p1.w;
    a10 += l1.x * p0.x + l1.y * p0.y + l1.z * p0.z + l1.w * p0.w;
    a11 += l1.x * p1.x + l1.y * p1.y + l1.z * p1.z + l1.w * p1.w;
  }
  X1[(k1 * 20 + k2) * 1024 + bc] = a00;
  X1[(k1 * 20 + k2 + 1) * 1024 + bc] = a01;
  X1[((k1 + 1) * 20 + k2) * 1024 + bc] = a10;
  X1[((k1 + 1) * 20 + k2 + 1) * 1024 + bc] = a11;
}

// ---- k2b: blur over batch axis (16, clamp)
__global__ void k2b_blurB(const float* __restrict__ X1, float* __restrict__ X1b) {
  int idx = blockIdx.x * 256 + threadIdx.x;
  if (idx >= 400 * 16 * 64) return;
  int c = idx & 63, b = (idx >> 6) & 15, m = idx >> 10;
  float g[9]; gauss9(g);
  float acc = 0.f;
#pragma unroll
  for (int t = 0; t < 9; ++t) {
    int bb = b - 4 + t; bb = bb < 0 ? 0 : (bb > 15 ? 15 : bb);
    acc += g[t] * X1[m * 1024 + bb * 64 + c];
  }
  X1b[idx] = acc;
}

// ---- k3: one block per mode m; O[(b*64+o)*400 + m]
__global__ void k3_mix(const float* __restrict__ X1b, const float* __restrict__ Wp,
                       const float* __restrict__ Wm, float* __restrict__ O) {
  __shared__ float Xa[1024], Xn[1024];
  int m = blockIdx.x, tid = threadIdx.x;
  int i = m / 20, j = m - i * 20;
  int nm = ((20 - i) % 20) * 20 + ((20 - j) % 20);
  for (int t = tid; t < 1024; t += 256) {
    Xa[t] = X1b[m * 1024 + t];
    Xn[t] = X1b[nm * 1024 + t];
  }
  __syncthreads();
  int o = tid & 63, b0 = tid >> 6;
  float acc[4] = {0.f, 0.f, 0.f, 0.f};
  for (int c = 0; c < 64; ++c) {
    float wp = Wp[(m * 64 + c) * 64 + o];
    float wm = Wm[(m * 64 + c) * 64 + o];
#pragma unroll
    for (int q = 0; q < 4; ++q) {
      int b = b0 + q * 4;
      acc[q] += Xa[b * 64 + c] * wp + Xn[b * 64 + c] * wm;
    }
  }
#pragma unroll
  for (int q = 0; q < 4; ++q) {
    int b = b0 + q * 4;
    O[(b * 64 + o) * 400 + m] = acc[q];
  }
}

// ---- k5b: per (b,o): Rs2[42][128] (C rows 0..20, S rows 21..41), Y = L2 * Rs2
__global__ void __launch_bounds__(256) k5b_final(const float* __restrict__ O,
                                                 const float* __restrict__ L2g,
                                                 const float* __restrict__ RB2g,
                                                 float* __restrict__ out) {
  __shared__ float Os[400];
  __shared__ float Rs[42 * 128];
  int bo = blockIdx.x, tid = threadIdx.x;
  for (int t = tid; t < 400; t += 256) Os[t] = O[bo * 400 + t];
  __syncthreads();
  const float4* Bc4 = (const float4*)RB2g;             // rows 0..20
  const float4* Bs4 = (const float4*)(RB2g + 21 * 128);
  for (int task = tid; task < 1344; task += 256) {
    int r = task >> 5, vq = task & 31;
    bool isS = (r >= 21);
    int A = isS ? (r - 21) : r;
    float4 acc = make_float4(0.f, 0.f, 0.f, 0.f);
    if (A < 20) {
      const float4* Bm = isS ? Bs4 : Bc4;
      float sgn = isS ? -1.f : 1.f;
#pragma unroll
      for (int k2 = 0; k2 < 20; ++k2) {
        float ov = sgn * Os[A * 20 + k2];
        float4 b = Bm[k2 * 32 + vq];
        acc.x += ov * b.x; acc.y += ov * b.y; acc.z += ov * b.z; acc.w += ov * b.w;
      }
    }
    if (A >= 1) {
      const float4* Bm = isS ? Bc4 : Bs4;
#pragma unroll
      for (int k2 = 0; k2 < 20; ++k2) {
        float ov = Os[(A - 1) * 20 + k2];
        float4 b = Bm[(k2 + 1) * 32 + vq];
        acc.x -= ov * b.x; acc.y -= ov * b.y; acc.z -= ov * b.z; acc.w -= ov * b.w;
      }
    }
    *(float4*)&Rs[r * 128 + vq * 4] = acc;
  }
  __syncthreads();
  int ug = tid >> 4, vg = tid & 15;
  int u0 = ug * 8, v0 = vg * 4;   // v-cols: v0..v0+3 and 64+v0..64+v0+3
  float acc[8][8];
#pragma unroll
  for (int i = 0; i < 8; ++i)
#pragma unroll
    for (int j = 0; j < 8; ++j) acc[i][j] = 0.f;
  for (int r = 0; r < 42; ++r) {
    float4 a0 = *(const float4*)(L2g + r * 128 + u0);
    float4 a1 = *(const float4*)(L2g + r * 128 + u0 + 4);
    float4 b0 = *(const float4*)&Rs[r * 128 + v0];
    float4 b1 = *(const float4*)&Rs[r * 128 + 64 + v0];
    float av[8] = {a0.x, a0.y, a0.z, a0.w, a1.x, a1.y, a1.z, a1.w};
    float bv[8] = {b0.x, b0.y, b0.z, b0.w, b1.x, b1.y, b1.z, b1.w};
#pragma unroll
    for (int i = 0; i < 8; ++i)
#pragma unroll
      for (int j = 0; j < 8; ++j) acc[i][j] += av[i] * bv[j];
  }
  long base = (long)bo * 16384;
#pragma unroll
  for (int i = 0; i < 8; ++i) {
    float4 s0 = make_float4(acc[i][0], acc[i][1], acc[i][2], acc[i][3]);
    float4 s1 = make_float4(acc[i][4], acc[i][5], acc[i][6], acc[i][7]);
    *(float4*)&out[base + (u0 + i) * 128 + v0] = s0;
    *(float4*)&out[base + (u0 + i) * 128 + 64 + v0] = s1;
  }
}

extern "C" void kernel_launch(void* const* d_in, const int* in_sizes, int n_in,
                              void* d_out, int out_size, void* d_ws, size_t ws_size,
                              hipStream_t stream) {
  const float* x = (const float*)d_in[0];    // (16,64,128,128)
  const float* w1 = (const float*)d_in[1];   // (64,64,20,20)
  float* out = (float*)d_out;                // (16,64,128,128)
  float* ws = (float*)d_ws;

  float* Wp = ws;                  // 1,638,400
  float* Wm = Wp + 1638400;        // 1,638,400
  float* Pw = Wm + 1638400;        // 5,242,880
  float* X1 = Pw + 5242880;        // 409,600
  float* X1b = X1 + 409600;        // 409,600
  float* O = X1b + 409600;         // 409,600
  float* wbT = O + 409600;         // 1,638,400
  float* Tg = wbT + 1638400;       // 5,120
  float* Lf2g = Tg + 5120;         // 10,240
  float* L2g = Lf2g + 10240;       // 5,376
  float* RB2g = L2g + 5376;        // 5,376   (total ~45 MB)

  hipLaunchKernelGGL(kinit, dim3(3), dim3(256), 0, stream, L2g, RB2g, Tg, Lf2g);
  hipLaunchKernelGGL(k0a_blurT, dim3(448), dim3(256), 0, stream, w1, wbT);
  hipLaunchKernelGGL(k0b_combine, dim3(400), dim3(256), 0, stream, wbT, Wp, Wm);
  hipLaunchKernelGGL(k1_rows, dim3(2048), dim3(192), 0, stream, x, Tg, Pw);
  hipLaunchKernelGGL(k2_modes, dim3(1024), dim3(256), 0, stream, Pw, Lf2g, X1);
  hipLaunchKernelGGL(k2b_blurB, dim3(1600), dim3(256), 0, stream, X1, X1b);
  hipLaunchKernelGGL(k3_mix, dim3(400), dim3(256), 0, stream, X1b, Wp, Wm, O);
  hipLaunchKernelGGL(k5b_final, dim3(1024), dim3(256), 0, stream, O, L2g, RB2g, out);
}